// Round 10
// baseline (694.138 us; speedup 1.0000x reference)
//
#include <hip/hip_runtime.h>
#include <hip/hip_fp8.h>

// GCN: N=100000 nodes, E=1600000 edges, F_IN=F_HID=64, F_OUT=16, fp32.
//
// R23 -> R24: gathers are settled (split-lane gather64 ~48us, scalar
// gather_l2 66.3us -- four restructures proved the forms). ~257us is
// invisible in top-5; arithmetic accounts ~55us of it (prelude/matnorms/
// gather16/scan), leaving the CSR build's edge DOUBLE-HANDLING (scatterA
// writes ppack 6.4MB; fillsort reads it twice on 98 CUs with 20-barrier
// scans) as the likely 60-110us block. R24 substitutes a direct build:
//   1. prelude: per-node deg count (global atomics, 16/addr) + cs1 colsum
//   2. scanN: one 1024-thr block, 98 nodes/thr, chunk+Hillis-Steele scan
//   3. scatter: csr[atomicAdd(&cur[d],1)] = src  (one pass, row order
//      within a row is irrelevant -- sums are order-independent)
// Deletes ppack/fillsort/scanA/hi-bucket machinery (19.2MB double-handling).
// deg/cur alias the dead-until-matnorm1 zb region (no workspace growth).
// Gathers/matnorms/gather16 byte-identical to R23 (anchors).

typedef float floatx2 __attribute__((ext_vector_type(2)));

__device__ __forceinline__ float rlane(float v, int k) {
  return __builtin_bit_cast(
      float, __builtin_amdgcn_readlane(__builtin_bit_cast(int, v), k));
}
__device__ __forceinline__ unsigned char f2fp8(float f) {
  __hip_fp8_e4m3 t(f);                // RNE, saturate-to-finite (OCP)
  return (unsigned char)t.__x;
}
// hardware OCP e4m3 -> f32 (gfx950); exact fallback via f16-embedding.
__device__ __forceinline__ float fp8tof(unsigned v) {
#if __has_builtin(__builtin_amdgcn_cvt_f32_fp8)
  return __builtin_amdgcn_cvt_f32_fp8((int)v, 0);
#else
  const unsigned h = ((v << 8) & 0x8000u) | ((v << 7) & 0x3f80u);
  __half_raw hr; hr.x = (unsigned short)h;
  return (float)__half(hr) * 256.0f;
#endif
}
// packed pair decode: 2 fp8 bytes -> 2 floats in one instruction
__device__ __forceinline__ floatx2 fp8x2tof(unsigned short p) {
#if __has_builtin(__builtin_amdgcn_cvt_pk_f32_fp8)
  return __builtin_amdgcn_cvt_pk_f32_fp8((int)(unsigned)p, false);
#else
  floatx2 r; r.x = fp8tof(p & 0xffu); r.y = fp8tof(p >> 8); return r;
#endif
}

// ------- prelude: per-node degree count + column sums of feat -------
__global__ __launch_bounds__(256) void prelude_kernel(
    const int* __restrict__ dst, int* __restrict__ deg, int E,
    const float* __restrict__ x, float* __restrict__ cs, int n4) {
  __shared__ float lds[16][64];
  const int t = threadIdx.x;
  const int stride = gridDim.x * blockDim.x;
  for (int e = blockIdx.x * blockDim.x + t; e < E; e += stride)
    atomicAdd(&deg[__builtin_nontemporal_load(&dst[e])], 1);

  float s0 = 0.f, s1 = 0.f, s2 = 0.f, s3 = 0.f;
  for (int i = blockIdx.x * blockDim.x + t; i < n4; i += stride) {
    float4 v = ((const float4*)x)[i];
    s0 += v.x; s1 += v.y; s2 += v.z; s3 += v.w;
  }
  const int r = t >> 4;
  const int cq = (t & 15) * 4;
  lds[r][cq + 0] = s0; lds[r][cq + 1] = s1; lds[r][cq + 2] = s2; lds[r][cq + 3] = s3;
  __syncthreads();
  if (t < 64) {
    float tot = 0.f;
    #pragma unroll
    for (int rr = 0; rr < 16; ++rr) tot += lds[rr][t];
    unsafeAtomicAdd(&cs[t], tot);
  }
}

// ------- scanN: exclusive prefix over deg[N] -> rowstart, cur (1 block) -------
__global__ __launch_bounds__(1024) void scanN_kernel(
    const int* __restrict__ deg, int* __restrict__ rowstart,
    int* __restrict__ cur, int N) {
  __shared__ int bs[1024];
  const int t = threadIdx.x;
  const int per = (N + 1023) >> 10;
  const int lo = t * per;
  const int hi = (lo + per < N) ? (lo + per) : N;
  int s = 0;
  for (int i = lo; i < hi; ++i) s += deg[i];
  bs[t] = s;
  __syncthreads();
  int acc = s;
  for (int off = 1; off < 1024; off <<= 1) {
    const int add = (t >= off) ? bs[t - off] : 0;
    __syncthreads();
    acc += add;
    bs[t] = acc;
    __syncthreads();
  }
  int run = acc - s;                 // exclusive prefix of this chunk
  for (int i = lo; i < hi; ++i) {
    rowstart[i] = run; cur[i] = run; run += deg[i];
  }
  if (t == 1023) rowstart[N] = run;  // == E
}

// ------- scatter: csr[cur[d]++] = src  (direct CSR fill, one pass) -------
__global__ __launch_bounds__(256) void scatter_kernel(
    const int* __restrict__ src, const int* __restrict__ dst,
    int* __restrict__ cur, int* __restrict__ csr, int E) {
  const int stride = gridDim.x * blockDim.x;
  for (int e = blockIdx.x * blockDim.x + threadIdx.x; e < E; e += stride) {
    const int d = __builtin_nontemporal_load(&dst[e]);
    const int s = __builtin_nontemporal_load(&src[e]);
    csr[atomicAdd(&cur[d], 1)] = s;
  }
}

// ------- layer1: z = (x @ W) * rinv - cm, fp8 out; 4-chain FMA -------
__global__ __launch_bounds__(256) void matnorm_kernel(
    const float* x, const float* __restrict__ W,
    const float* __restrict__ cs, unsigned char* __restrict__ z,
    int N, float invN) {
  const int lane = threadIdx.x & 63;
  const int wid  = blockIdx.x * (blockDim.x >> 6) + (threadIdx.x >> 6);
  const int nw   = gridDim.x * (blockDim.x >> 6);

  float w[64];
  float cm0 = 0.f, cm1 = 0.f, cm2 = 0.f, cm3 = 0.f;
  #pragma unroll
  for (int k = 0; k < 64; k += 4) {
    w[k + 0] = W[(k + 0) * 64 + lane];
    w[k + 1] = W[(k + 1) * 64 + lane];
    w[k + 2] = W[(k + 2) * 64 + lane];
    w[k + 3] = W[(k + 3) * 64 + lane];
    cm0 = fmaf(cs[k + 0], w[k + 0], cm0);
    cm1 = fmaf(cs[k + 1], w[k + 1], cm1);
    cm2 = fmaf(cs[k + 2], w[k + 2], cm2);
    cm3 = fmaf(cs[k + 3], w[k + 3], cm3);
  }
  const float cm = ((cm0 + cm1) + (cm2 + cm3)) * invN;

  for (int row = wid; row < N; row += nw) {
    const float xv = x[(size_t)row * 64 + lane];
    float ss = xv * xv;
    #pragma unroll
    for (int m = 1; m < 64; m <<= 1) ss += __shfl_xor(ss, m, 64);
    const float rinv = 1.0f / sqrtf(1e-6f + ss);
    float a0 = 0.f, a1 = 0.f, a2 = 0.f, a3 = 0.f;
    #pragma unroll
    for (int k = 0; k < 64; k += 4) {
      a0 = fmaf(rlane(xv, k + 0), w[k + 0], a0);
      a1 = fmaf(rlane(xv, k + 1), w[k + 1], a1);
      a2 = fmaf(rlane(xv, k + 2), w[k + 2], a2);
      a3 = fmaf(rlane(xv, k + 3), w[k + 3], a3);
    }
    const float acc = (a0 + a1) + (a2 + a3);
    z[(size_t)row * 64 + lane] = f2fp8(acc * rinv - cm);
  }
}

// ------- layer2: z2' = (x @ W) * rinv (UNcentered), fp8 out; cs += colsum(x) -------
__global__ __launch_bounds__(256) void matnorm2_kernel(
    const float* x, const float* __restrict__ W,
    float* __restrict__ cs, unsigned char* __restrict__ z, int N) {
  __shared__ float lred[4][64];
  const int lane = threadIdx.x & 63;
  const int wv   = threadIdx.x >> 6;
  const int wid  = blockIdx.x * (blockDim.x >> 6) + wv;
  const int nw   = gridDim.x * (blockDim.x >> 6);

  float w[64];
  #pragma unroll
  for (int k = 0; k < 64; k += 4) {
    w[k + 0] = W[(k + 0) * 64 + lane];
    w[k + 1] = W[(k + 1) * 64 + lane];
    w[k + 2] = W[(k + 2) * 64 + lane];
    w[k + 3] = W[(k + 3) * 64 + lane];
  }

  float csum = 0.f;
  for (int row = wid; row < N; row += nw) {
    const float xv = x[(size_t)row * 64 + lane];
    csum += xv;
    float ss = xv * xv;
    #pragma unroll
    for (int m = 1; m < 64; m <<= 1) ss += __shfl_xor(ss, m, 64);
    const float rinv = 1.0f / sqrtf(1e-6f + ss);
    float a0 = 0.f, a1 = 0.f, a2 = 0.f, a3 = 0.f;
    #pragma unroll
    for (int k = 0; k < 64; k += 4) {
      a0 = fmaf(rlane(xv, k + 0), w[k + 0], a0);
      a1 = fmaf(rlane(xv, k + 1), w[k + 1], a1);
      a2 = fmaf(rlane(xv, k + 2), w[k + 2], a2);
      a3 = fmaf(rlane(xv, k + 3), w[k + 3], a3);
    }
    const float acc = (a0 + a1) + (a2 + a3);
    z[(size_t)row * 64 + lane] = f2fp8(acc * rinv);
  }
  lred[wv][lane] = csum;
  __syncthreads();
  if (threadIdx.x < 64) {
    const float tot = lred[0][lane] + lred[1][lane] + lred[2][lane] + lred[3][lane];
    unsafeAtomicAdd(&cs[lane], tot);
  }
}

// ------- cm2[m] = invN * sum_k cs2[k] * W2[k][m]  (1 wave) -------
__global__ void cm2_kernel(const float* __restrict__ cs,
                           const float* __restrict__ W,
                           float* __restrict__ cm2, float invN) {
  const int m = threadIdx.x;   // 64
  float a0 = 0.f, a1 = 0.f, a2 = 0.f, a3 = 0.f;
  #pragma unroll
  for (int k = 0; k < 64; k += 4) {
    a0 = fmaf(cs[k + 0], W[(k + 0) * 64 + m], a0);
    a1 = fmaf(cs[k + 1], W[(k + 1) * 64 + m], a1);
    a2 = fmaf(cs[k + 2], W[(k + 2) * 64 + m], a2);
    a3 = fmaf(cs[k + 3], W[(k + 3) * 64 + m], a3);
  }
  cm2[m] = ((a0 + a1) + (a2 + a3)) * invN;
}

// ------- gather64 (split-lane pair): agg[d] = relu(z[d] + b + sum z[src]) -------
// Wave = 2 nodes; half h serves node n0+h, lane owns features (2*il, 2*il+1).
// One ushort VMEM per j serves one edge of EACH half (0.5 instr/edge).
// Proven form for gather64 (R22/R23) -- do not restructure.
__global__ __launch_bounds__(256) void gather64_kernel(
    const unsigned char* __restrict__ z, const float* __restrict__ b,
    const int* __restrict__ rowstart, const int* __restrict__ csr,
    float* __restrict__ agg, int N) {
  const int lane = threadIdx.x & 63;
  const int h    = lane >> 5;
  const int il   = lane & 31;
  const int f0   = il << 1;
  const int pair = blockIdx.x * (blockDim.x >> 6) + (threadIdx.x >> 6);
  const int n0 = pair << 1;
  if (n0 >= N) return;
  const int node = n0 + h;
  const bool hv = (node < N);
  const int start = hv ? rowstart[node] : 0;
  const int end   = hv ? rowstart[node + 1] : 0;
  const int deg   = end - start;
  const int degA = __builtin_amdgcn_readfirstlane(deg);
  const int degB = __builtin_amdgcn_readlane(deg, 32);
  const int maxdeg = degA > degB ? degA : degB;

  const unsigned char* zp = z + f0;
  const unsigned short sv =
      hv ? *(const unsigned short*)(zp + (size_t)node * 64) : (unsigned short)0;

  float a00 = 0.f, a01 = 0.f, a10 = 0.f, a11 = 0.f;
  for (int w0 = 0; w0 < maxdeg; w0 += 32) {
    const int ei = start + w0 + il;
    const int safe = (ei < end) ? ei : (end > start ? end - 1 : 0);
    const int cidx = csr[safe];
    const int rem = maxdeg - w0;
    const int nloc = rem < 32 ? rem : 32;
    int j0 = 0;
    for (; j0 + 16 <= nloc; j0 += 16) {
      int idx[16];
      #pragma unroll
      for (int j = 0; j < 16; ++j)
        idx[j] = __shfl(cidx, (h << 5) + j0 + j, 64);
      unsigned short hh[16];
      #pragma unroll
      for (int j = 0; j < 16; ++j)
        hh[j] = *(const unsigned short*)(zp + (size_t)(unsigned)idx[j] * 64u);
      #pragma unroll
      for (int j = 0; j < 16; ++j) {
        const unsigned short m = (w0 + j0 + j < deg) ? hh[j] : (unsigned short)0;
        const floatx2 v = fp8x2tof(m);
        if (j & 1) { a10 += v.x; a11 += v.y; }
        else       { a00 += v.x; a01 += v.y; }
      }
    }
    for (; j0 + 4 <= nloc; j0 += 4) {
      int idx[4];
      #pragma unroll
      for (int j = 0; j < 4; ++j)
        idx[j] = __shfl(cidx, (h << 5) + j0 + j, 64);
      unsigned short hh[4];
      #pragma unroll
      for (int j = 0; j < 4; ++j)
        hh[j] = *(const unsigned short*)(zp + (size_t)(unsigned)idx[j] * 64u);
      #pragma unroll
      for (int j = 0; j < 4; ++j) {
        const unsigned short m = (w0 + j0 + j < deg) ? hh[j] : (unsigned short)0;
        const floatx2 v = fp8x2tof(m);
        if (j & 1) { a10 += v.x; a11 += v.y; }
        else       { a00 += v.x; a01 += v.y; }
      }
    }
    for (; j0 < nloc; ++j0) {
      const int idx = __shfl(cidx, (h << 5) + j0, 64);
      const unsigned short hh =
          *(const unsigned short*)(zp + (size_t)(unsigned)idx * 64u);
      const unsigned short m = (w0 + j0 < deg) ? hh : (unsigned short)0;
      const floatx2 v = fp8x2tof(m);
      a00 += v.x; a01 += v.y;
    }
  }
  if (hv) {
    const floatx2 sf = fp8x2tof(sv);
    const float2 bb = *(const float2*)(b + f0);
    float2 st;
    st.x = fmaxf(sf.x + bb.x + a00 + a10, 0.f);
    st.y = fmaxf(sf.y + bb.y + a01 + a11, 0.f);
    *(float2*)(agg + (size_t)node * 64 + f0) = st;
  }
}

// ------- gather_l2: o = relu(sum z2' - (deg+1)*cm2 + b2); z3 = o @ W3 (fp8) -------
// R19/R21 proven scalar form: one node/wave, 16/4/1 chunks, scalar-uniform
// csr, byte loads, HW fp8 decode; transposed-matvec epilogue. Every
// restructure lost (R15/R17/R20/R22) -- do not touch.
__global__ __launch_bounds__(256) void gather_l2_kernel(
    const unsigned char* __restrict__ z2, const float* __restrict__ b2,
    const float* __restrict__ W3, const float* __restrict__ cm2,
    const int* __restrict__ rowstart, const int* __restrict__ csr,
    unsigned char* __restrict__ z3, int N) {
  const int lane = threadIdx.x & 63;
  int node = blockIdx.x * (blockDim.x >> 6) + (threadIdx.x >> 6);
  if (node >= N) return;
  node = __builtin_amdgcn_readfirstlane(node);
  // stage W3 row `lane` early (independent of the gather; 4 VMEM total)
  float4 w4[4];
  #pragma unroll
  for (int q = 0; q < 4; ++q)
    w4[q] = ((const float4*)(W3 + lane * 16))[q];
  const float cml = cm2[lane];

  const int start = rowstart[node];
  const int end   = rowstart[node + 1];
  const unsigned char hs = z2[(size_t)node * 64 + lane];
  float a0 = 0.f, a1 = 0.f, a2 = 0.f, a3 = 0.f;
  int e = start;
  for (; e + 16 <= end; e += 16) {
    unsigned char h[16];
    #pragma unroll
    for (int j = 0; j < 16; ++j) h[j] = z2[(size_t)csr[e + j] * 64 + lane];
    #pragma unroll
    for (int j = 0; j < 16; j += 4) {
      a0 += fp8tof(h[j + 0]); a1 += fp8tof(h[j + 1]);
      a2 += fp8tof(h[j + 2]); a3 += fp8tof(h[j + 3]);
    }
  }
  for (; e + 4 <= end; e += 4) {
    unsigned char h[4];
    #pragma unroll
    for (int j = 0; j < 4; ++j) h[j] = z2[(size_t)csr[e + j] * 64 + lane];
    a0 += fp8tof(h[0]); a1 += fp8tof(h[1]); a2 += fp8tof(h[2]); a3 += fp8tof(h[3]);
  }
  for (; e < end; ++e) a0 += fp8tof(z2[(size_t)csr[e] * 64 + lane]);
  const float sum = (a0 + a1) + (a2 + a3);
  const float corr = (float)(end - start + 1) * cml;   // deg+1 rows pulled cm2
  const float o = fmaxf(fp8tof(hs) + b2[lane] + sum - corr, 0.f);

  // 16 partials: p[m] = o * W3[lane][m]
  float p[16];
  #pragma unroll
  for (int q = 0; q < 4; ++q) {
    p[4 * q + 0] = o * w4[q].x;
    p[4 * q + 1] = o * w4[q].y;
    p[4 * q + 2] = o * w4[q].z;
    p[4 * q + 3] = o * w4[q].w;
  }
  // split-butterfly: xor 1 (16->8), xor 2 (8->4), xor 4 (4->2), xor 8 (2->1)
  {
    const bool up = (lane & 1);
    #pragma unroll
    for (int m = 0; m < 8; ++m) {
      const float mine = up ? p[m + 8] : p[m];
      const float give = up ? p[m] : p[m + 8];
      p[m] = mine + __shfl_xor(give, 1, 64);
    }
  }
  {
    const bool up = (lane & 2);
    #pragma unroll
    for (int m = 0; m < 4; ++m) {
      const float mine = up ? p[m + 4] : p[m];
      const float give = up ? p[m] : p[m + 4];
      p[m] = mine + __shfl_xor(give, 2, 64);
    }
  }
  {
    const bool up = (lane & 4);
    #pragma unroll
    for (int m = 0; m < 2; ++m) {
      const float mine = up ? p[m + 2] : p[m];
      const float give = up ? p[m] : p[m + 2];
      p[m] = mine + __shfl_xor(give, 4, 64);
    }
  }
  {
    const bool up = (lane & 8);
    const float mine = up ? p[1] : p[0];
    const float give = up ? p[0] : p[1];
    p[0] = mine + __shfl_xor(give, 8, 64);
  }
  // pure reductions across remaining lane bits
  p[0] += __shfl_xor(p[0], 16, 64);
  p[0] += __shfl_xor(p[0], 32, 64);

  if (lane < 16) {
    // lane l holds output column bitrev4(l)
    const int j = ((lane & 1) << 3) | ((lane & 2) << 1) |
                  ((lane & 4) >> 1) | ((lane & 8) >> 3);
    z3[(size_t)node * 16 + j] = f2fp8(p[0]);
  }
}

// ------- gather16: out[d] = z3[d] + b3 + sum z3[src]; 16 feat x 4 edge-groups -------
__global__ __launch_bounds__(256) void gather16_kernel(
    const unsigned char* __restrict__ z3, const float* __restrict__ b3,
    const int* __restrict__ rowstart, const int* __restrict__ csr,
    float* __restrict__ out, int N) {
  const int lane = threadIdx.x & 63;
  const int f = lane & 15;
  const int g = lane >> 4;
  int node = blockIdx.x * (blockDim.x >> 6) + (threadIdx.x >> 6);
  if (node >= N) return;
  node = __builtin_amdgcn_readfirstlane(node);
  const int start = rowstart[node];
  const int end   = rowstart[node + 1];
  float acc0 = 0.f, acc1 = 0.f;
  int e = start + g;
  for (; e + 4 < end; e += 8) {
    acc0 += fp8tof(z3[(size_t)csr[e] * 16 + f]);
    acc1 += fp8tof(z3[(size_t)csr[e + 4] * 16 + f]);
  }
  if (e < end) acc0 += fp8tof(z3[(size_t)csr[e] * 16 + f]);
  float acc = acc0 + acc1;
  acc += __shfl_xor(acc, 16, 64);
  acc += __shfl_xor(acc, 32, 64);
  if (lane < 16)
    out[(size_t)node * 16 + f] = fp8tof(z3[(size_t)node * 16 + f]) + b3[f] + acc;
}

extern "C" void kernel_launch(void* const* d_in, const int* in_sizes, int n_in,
                              void* d_out, int out_size, void* d_ws, size_t ws_size,
                              hipStream_t stream) {
  const float* feat = (const float*)d_in[0];
  const float* W1 = (const float*)d_in[1];
  const float* b1 = (const float*)d_in[2];
  const float* W2 = (const float*)d_in[3];
  const float* b2 = (const float*)d_in[4];
  const float* W3 = (const float*)d_in[5];
  const float* b3 = (const float*)d_in[6];
  const int* src = (const int*)d_in[7];
  const int* dst = (const int*)d_in[8];
  const int N = in_sizes[0] / 64;
  const int E = in_sizes[7];
  float* out = (float*)d_out;

  // workspace layout
  float* B            = (float*)d_ws;                     // agg1, N*64 fp32
  unsigned char* zb   = (unsigned char*)(B + (size_t)N * 64);   // z1/z2' fp8 N*64
  unsigned char* z3b  = zb + (size_t)N * 64;              // z3, N*16 fp8
  float* cs1 = (float*)(z3b + (size_t)N * 16);            // 64 } one memset
  float* cs2 = cs1 + 64;                                  // 64 } (512 B)
  float* cm2w = cs2 + 64;                                 // 64 (no memset needed)
  int* rowstart = (int*)(cm2w + 64);                      // N+1
  int* csr      = rowstart + N + 1;                       // E
  // deg/cur alias zb (dead until matnorm1 writes it, after scatter):
  // 2*N*4 = 800 KB <= N*64 = 6.4 MB
  int* deg = (int*)zb;
  int* cur = deg + N;

  const int node_blocks = (N + 3) / 4;  // 4 waves of 64 per block
  const int npairs = (N + 1) / 2;
  const int pair_blocks = (npairs + 3) / 4;  // 4 pair-waves per block
  const float invN = 1.0f / (float)N;

  // ---- CSR build (direct) + layer-1 colsum ----
  hipMemsetAsync(deg, 0, (size_t)N * sizeof(int), stream);
  hipMemsetAsync(cs1, 0, 128 * sizeof(float), stream);   // cs1 + cs2
  prelude_kernel<<<512, 256, 0, stream>>>(dst, deg, E, feat, cs1, N * 16);
  scanN_kernel<<<1, 1024, 0, stream>>>(deg, rowstart, cur, N);
  scatter_kernel<<<512, 256, 0, stream>>>(src, dst, cur, csr, E);

  // ---- layer 1 (split-lane pair gather) ----
  matnorm_kernel<<<1024, 256, 0, stream>>>(feat, W1, cs1, zb, N, invN);
  gather64_kernel<<<pair_blocks, 256, 0, stream>>>(zb, b1, rowstart, csr, B, N);

  // ---- layer 2: matnorm2 emits UNcentered z2' and accumulates cs2 itself ----
  matnorm2_kernel<<<1024, 256, 0, stream>>>(B, W2, cs2, zb, N);
  cm2_kernel<<<1, 64, 0, stream>>>(cs2, W2, cm2w, invN);
  gather_l2_kernel<<<node_blocks, 256, 0, stream>>>(zb, b2, W3, cm2w, rowstart,
                                                    csr, z3b, N);

  // ---- layer 3 final aggregation ----
  gather16_kernel<<<node_blocks, 256, 0, stream>>>(z3b, b3, rowstart, csr, out, N);
}

// Round 13
// 368.704 us; speedup vs baseline: 1.8826x; 1.8826x over previous
//
#include <hip/hip_runtime.h>
#include <hip/hip_fp8.h>

// GCN: N=100000 nodes, E=1600000 edges, F_IN=F_HID=64, F_OUT=16, fp32.
//
// R26: the 1024-thread half-bucket fillsort killed the container twice
// (source-correlated; audit clean but two failures vs 11 passes elsewhere).
// Same THEORY (98 blocks on 256 CUs is the build's parallelism defect),
// SAFER MECHANICS: 512-thread blocks, ALL threads participate in every
// phase (no predicated scan/barriers -- codegen mirrors the proven R23
// fillsort: 4-deep ILP batches, same loop shapes, 512 bins + half filter).
// 196 blocks x 8 waves = same wave count as R23's 98 x 16, but 2x CU
// coverage. half-1 base = ehi - own_total (no sibling comm). Everything
// else byte-identical to the R23 source (371.6us measured).
// If this fails again: experiment declared cursed, full R23 revert next.

#define NHB 128     // max hi-buckets of 1024 nodes (N <= 131072); hi = dst >> 10

typedef float floatx2 __attribute__((ext_vector_type(2)));

__device__ __forceinline__ float rlane(float v, int k) {
  return __builtin_bit_cast(
      float, __builtin_amdgcn_readlane(__builtin_bit_cast(int, v), k));
}
__device__ __forceinline__ unsigned char f2fp8(float f) {
  __hip_fp8_e4m3 t(f);                // RNE, saturate-to-finite (OCP)
  return (unsigned char)t.__x;
}
// hardware OCP e4m3 -> f32 (gfx950); exact fallback via f16-embedding.
__device__ __forceinline__ float fp8tof(unsigned v) {
#if __has_builtin(__builtin_amdgcn_cvt_f32_fp8)
  return __builtin_amdgcn_cvt_f32_fp8((int)v, 0);
#else
  const unsigned h = ((v << 8) & 0x8000u) | ((v << 7) & 0x3f80u);
  __half_raw hr; hr.x = (unsigned short)h;
  return (float)__half(hr) * 256.0f;
#endif
}
// packed pair decode: 2 fp8 bytes -> 2 floats in one instruction
__device__ __forceinline__ floatx2 fp8x2tof(unsigned short p) {
#if __has_builtin(__builtin_amdgcn_cvt_pk_f32_fp8)
  return __builtin_amdgcn_cvt_pk_f32_fp8((int)(unsigned)p, false);
#else
  floatx2 r; r.x = fp8tof(p & 0xffu); r.y = fp8tof(p >> 8); return r;
#endif
}

// ------- prelude: cntA histogram of dst (hi-buckets) + column sums of feat -------
__global__ __launch_bounds__(256) void prelude_kernel(
    const int* __restrict__ dst, int* __restrict__ cntA, int E,
    const float* __restrict__ x, float* __restrict__ cs, int n4) {
  __shared__ int lc[NHB];
  __shared__ float lds[16][64];
  const int t = threadIdx.x;
  if (t < NHB) lc[t] = 0;
  __syncthreads();
  const int stride = gridDim.x * blockDim.x;
  for (int e = blockIdx.x * blockDim.x + t; e < E; e += stride)
    atomicAdd(&lc[__builtin_nontemporal_load(&dst[e]) >> 10], 1);

  float s0 = 0.f, s1 = 0.f, s2 = 0.f, s3 = 0.f;
  for (int i = blockIdx.x * blockDim.x + t; i < n4; i += stride) {
    float4 v = ((const float4*)x)[i];
    s0 += v.x; s1 += v.y; s2 += v.z; s3 += v.w;
  }
  const int r = t >> 4;
  const int cq = (t & 15) * 4;
  lds[r][cq + 0] = s0; lds[r][cq + 1] = s1; lds[r][cq + 2] = s2; lds[r][cq + 3] = s3;
  __syncthreads();
  if (t < NHB && lc[t]) atomicAdd(&cntA[t], lc[t]);
  if (t < 64) {
    float tot = 0.f;
    #pragma unroll
    for (int rr = 0; rr < 16; ++rr) tot += lds[rr][t];
    unsafeAtomicAdd(&cs[t], tot);
  }
}

// ------- layer1: z = (x @ W) * rinv - cm, fp8 out; 4-chain FMA -------
__global__ __launch_bounds__(256) void matnorm_kernel(
    const float* x, const float* __restrict__ W,
    const float* __restrict__ cs, unsigned char* __restrict__ z,
    int N, float invN) {
  const int lane = threadIdx.x & 63;
  const int wid  = blockIdx.x * (blockDim.x >> 6) + (threadIdx.x >> 6);
  const int nw   = gridDim.x * (blockDim.x >> 6);

  float w[64];
  float cm0 = 0.f, cm1 = 0.f, cm2 = 0.f, cm3 = 0.f;
  #pragma unroll
  for (int k = 0; k < 64; k += 4) {
    w[k + 0] = W[(k + 0) * 64 + lane];
    w[k + 1] = W[(k + 1) * 64 + lane];
    w[k + 2] = W[(k + 2) * 64 + lane];
    w[k + 3] = W[(k + 3) * 64 + lane];
    cm0 = fmaf(cs[k + 0], w[k + 0], cm0);
    cm1 = fmaf(cs[k + 1], w[k + 1], cm1);
    cm2 = fmaf(cs[k + 2], w[k + 2], cm2);
    cm3 = fmaf(cs[k + 3], w[k + 3], cm3);
  }
  const float cm = ((cm0 + cm1) + (cm2 + cm3)) * invN;

  for (int row = wid; row < N; row += nw) {
    const float xv = x[(size_t)row * 64 + lane];
    float ss = xv * xv;
    #pragma unroll
    for (int m = 1; m < 64; m <<= 1) ss += __shfl_xor(ss, m, 64);
    const float rinv = 1.0f / sqrtf(1e-6f + ss);
    float a0 = 0.f, a1 = 0.f, a2 = 0.f, a3 = 0.f;
    #pragma unroll
    for (int k = 0; k < 64; k += 4) {
      a0 = fmaf(rlane(xv, k + 0), w[k + 0], a0);
      a1 = fmaf(rlane(xv, k + 1), w[k + 1], a1);
      a2 = fmaf(rlane(xv, k + 2), w[k + 2], a2);
      a3 = fmaf(rlane(xv, k + 3), w[k + 3], a3);
    }
    const float acc = (a0 + a1) + (a2 + a3);
    z[(size_t)row * 64 + lane] = f2fp8(acc * rinv - cm);
  }
}

// ------- layer2: z2' = (x @ W) * rinv (UNcentered), fp8 out; cs += colsum(x) -------
__global__ __launch_bounds__(256) void matnorm2_kernel(
    const float* x, const float* __restrict__ W,
    float* __restrict__ cs, unsigned char* __restrict__ z, int N) {
  __shared__ float lred[4][64];
  const int lane = threadIdx.x & 63;
  const int wv   = threadIdx.x >> 6;
  const int wid  = blockIdx.x * (blockDim.x >> 6) + wv;
  const int nw   = gridDim.x * (blockDim.x >> 6);

  float w[64];
  #pragma unroll
  for (int k = 0; k < 64; k += 4) {
    w[k + 0] = W[(k + 0) * 64 + lane];
    w[k + 1] = W[(k + 1) * 64 + lane];
    w[k + 2] = W[(k + 2) * 64 + lane];
    w[k + 3] = W[(k + 3) * 64 + lane];
  }

  float csum = 0.f;
  for (int row = wid; row < N; row += nw) {
    const float xv = x[(size_t)row * 64 + lane];
    csum += xv;
    float ss = xv * xv;
    #pragma unroll
    for (int m = 1; m < 64; m <<= 1) ss += __shfl_xor(ss, m, 64);
    const float rinv = 1.0f / sqrtf(1e-6f + ss);
    float a0 = 0.f, a1 = 0.f, a2 = 0.f, a3 = 0.f;
    #pragma unroll
    for (int k = 0; k < 64; k += 4) {
      a0 = fmaf(rlane(xv, k + 0), w[k + 0], a0);
      a1 = fmaf(rlane(xv, k + 1), w[k + 1], a1);
      a2 = fmaf(rlane(xv, k + 2), w[k + 2], a2);
      a3 = fmaf(rlane(xv, k + 3), w[k + 3], a3);
    }
    const float acc = (a0 + a1) + (a2 + a3);
    z[(size_t)row * 64 + lane] = f2fp8(acc * rinv);
  }
  lred[wv][lane] = csum;
  __syncthreads();
  if (threadIdx.x < 64) {
    const float tot = lred[0][lane] + lred[1][lane] + lred[2][lane] + lred[3][lane];
    unsafeAtomicAdd(&cs[lane], tot);
  }
}

// ------- cm2[m] = invN * sum_k cs2[k] * W2[k][m]  (1 wave) -------
__global__ void cm2_kernel(const float* __restrict__ cs,
                           const float* __restrict__ W,
                           float* __restrict__ cm2, float invN) {
  const int m = threadIdx.x;   // 64
  float a0 = 0.f, a1 = 0.f, a2 = 0.f, a3 = 0.f;
  #pragma unroll
  for (int k = 0; k < 64; k += 4) {
    a0 = fmaf(cs[k + 0], W[(k + 0) * 64 + m], a0);
    a1 = fmaf(cs[k + 1], W[(k + 1) * 64 + m], a1);
    a2 = fmaf(cs[k + 2], W[(k + 2) * 64 + m], a2);
    a3 = fmaf(cs[k + 3], W[(k + 3) * 64 + m], a3);
  }
  cm2[m] = ((a0 + a1) + (a2 + a3)) * invN;
}

// ================= CSR build: hi-bucket radix + LDS counting sort =================
// Edge packed as (src << 10) | (dst & 1023): src < 2^17 -> 27 bits used.

// 128-thread LDS Hillis-Steele exclusive scan over the hi-bucket counts.
__global__ void scanA_kernel(const int* __restrict__ cntA,
                             int* __restrict__ baseA, int* __restrict__ curA,
                             int NHI) {
  __shared__ int s[NHB];
  const int t = threadIdx.x;   // 128
  const int v = (t < NHI) ? cntA[t] : 0;
  s[t] = v;
  __syncthreads();
  int acc = v;
  for (int off = 1; off < NHB; off <<= 1) {
    const int add = (t >= off) ? s[t - off] : 0;
    __syncthreads();
    acc += add;
    s[t] = acc;
    __syncthreads();
  }
  const int excl = acc - v;
  if (t < NHI) { baseA[t] = excl; curA[t] = excl; }
  if (t == NHI - 1) baseA[NHI] = acc;
}

#define TILE 2048
#define CAPA 48   // per-tile per-bucket mean 21, sigma 4.6 -> ~6 sigma + spill
__global__ __launch_bounds__(256) void scatterA_kernel(
    const int* __restrict__ src, const int* __restrict__ dst,
    int* __restrict__ curA, unsigned* __restrict__ ppack, int E) {
  __shared__ unsigned lpk[NHB][CAPA];
  __shared__ int lcnt[NHB], lbase[NHB];
  const int t = threadIdx.x;
  if (t < NHB) lcnt[t] = 0;
  __syncthreads();
  const int ntiles = (E + TILE - 1) / TILE;
  for (int tile = blockIdx.x; tile < ntiles; tile += gridDim.x) {
    const int base = tile * TILE;
    #pragma unroll
    for (int j = 0; j < TILE / 256; ++j) {
      const int e = base + j * 256 + t;   // coalesced
      if (e < E) {
        const int d = __builtin_nontemporal_load(&dst[e]);
        const int s = __builtin_nontemporal_load(&src[e]);
        const unsigned pw = ((unsigned)s << 10) | ((unsigned)d & 1023u);
        const int p = d >> 10;
        const int slot = atomicAdd(&lcnt[p], 1);
        if (slot < CAPA) lpk[p][slot] = pw;
        else ppack[atomicAdd(&curA[p], 1)] = pw;  // rare spill
      }
    }
    __syncthreads();
    if (t < NHB) {
      int c = lcnt[t]; if (c > CAPA) c = CAPA;
      lbase[t] = c ? atomicAdd(&curA[t], c) : 0;
      lcnt[t] = c;
    }
    __syncthreads();
    for (int p = 0; p < NHB; ++p) {
      const int c = lcnt[p];
      if (t < c) ppack[lbase[p] + t] = lpk[p][t];  // contiguous chunk
    }
    __syncthreads();
    if (t < NHB) lcnt[t] = 0;
    __syncthreads();
  }
}

// One workgroup (512 thr) per 512-node HALF-bucket. ALL threads participate
// in every phase (no predicated barriers). Filter parent ppack range by bit9
// of the low-10 dst bits; 512-bin LDS counting sort; 4-deep ILP like R23.
// half-1 base = ehi - own_total (half-0 rows precede half-1 in dst order).
__global__ __launch_bounds__(512) void fillsort_kernel(
    const unsigned* __restrict__ ppack, const int* __restrict__ baseA,
    int* __restrict__ rowstart, int* __restrict__ csr, int N, int E) {
  __shared__ int hist[512];
  __shared__ int bs[512];
  const int t = threadIdx.x;          // 512
  const int hb = blockIdx.x;          // half-bucket id
  const int parent = hb >> 1;
  const unsigned half = (unsigned)(hb & 1);
  const int nlo = hb << 9;            // first node of this half
  const int elo = baseA[parent], ehi = baseA[parent + 1];

  hist[t] = 0;
  __syncthreads();

  // phase 1: histogram own half (4 independent loads in flight)
  int e = elo + t;
  for (; e + 3 * 512 < ehi; e += 4 * 512) {
    const unsigned p0 = ppack[e],           p1 = ppack[e + 512];
    const unsigned p2 = ppack[e + 2 * 512], p3 = ppack[e + 3 * 512];
    if (((p0 >> 9) & 1u) == half) atomicAdd(&hist[p0 & 511u], 1);
    if (((p1 >> 9) & 1u) == half) atomicAdd(&hist[p1 & 511u], 1);
    if (((p2 >> 9) & 1u) == half) atomicAdd(&hist[p2 & 511u], 1);
    if (((p3 >> 9) & 1u) == half) atomicAdd(&hist[p3 & 511u], 1);
  }
  for (; e < ehi; e += 512) {
    const unsigned p = ppack[e];
    if (((p >> 9) & 1u) == half) atomicAdd(&hist[p & 511u], 1);
  }
  __syncthreads();

  // exclusive scan over 512 bins (all 512 threads; 9 rounds)
  const int c = hist[t];
  bs[t] = c;
  __syncthreads();
  for (int off = 1; off < 512; off <<= 1) {
    const int v = (t >= off) ? bs[t - off] : 0;
    __syncthreads();
    bs[t] += v;
    __syncthreads();
  }
  const int excl = bs[t] - c;
  const int total = bs[511];
  const int halfbase = half ? (ehi - total) : elo;

  hist[t] = excl;                     // LDS cursor
  const int n0 = nlo + t;
  if (n0 < N) rowstart[n0] = halfbase + excl;
  if (hb == 0 && t == 0) rowstart[N] = E;
  __syncthreads();

  // phase 2: place own half (csr window ~32KB, single CU owner)
  e = elo + t;
  for (; e + 3 * 512 < ehi; e += 4 * 512) {
    const unsigned p0 = ppack[e],           p1 = ppack[e + 512];
    const unsigned p2 = ppack[e + 2 * 512], p3 = ppack[e + 3 * 512];
    if (((p0 >> 9) & 1u) == half)
      csr[halfbase + atomicAdd(&hist[p0 & 511u], 1)] = (int)(p0 >> 10);
    if (((p1 >> 9) & 1u) == half)
      csr[halfbase + atomicAdd(&hist[p1 & 511u], 1)] = (int)(p1 >> 10);
    if (((p2 >> 9) & 1u) == half)
      csr[halfbase + atomicAdd(&hist[p2 & 511u], 1)] = (int)(p2 >> 10);
    if (((p3 >> 9) & 1u) == half)
      csr[halfbase + atomicAdd(&hist[p3 & 511u], 1)] = (int)(p3 >> 10);
  }
  for (; e < ehi; e += 512) {
    const unsigned p = ppack[e];
    if (((p >> 9) & 1u) == half)
      csr[halfbase + atomicAdd(&hist[p & 511u], 1)] = (int)(p >> 10);
  }
}

// ------- gather64 (split-lane pair): agg[d] = relu(z[d] + b + sum z[src]) -------
// Wave = 2 nodes; half h serves node n0+h, lane owns features (2*il, 2*il+1).
// One ushort VMEM per j serves one edge of EACH half (0.5 instr/edge).
// Proven form for gather64 (R22/R23) -- do not restructure.
__global__ __launch_bounds__(256) void gather64_kernel(
    const unsigned char* __restrict__ z, const float* __restrict__ b,
    const int* __restrict__ rowstart, const int* __restrict__ csr,
    float* __restrict__ agg, int N) {
  const int lane = threadIdx.x & 63;
  const int h    = lane >> 5;
  const int il   = lane & 31;
  const int f0   = il << 1;
  const int pair = blockIdx.x * (blockDim.x >> 6) + (threadIdx.x >> 6);
  const int n0 = pair << 1;
  if (n0 >= N) return;
  const int node = n0 + h;
  const bool hv = (node < N);
  const int start = hv ? rowstart[node] : 0;
  const int end   = hv ? rowstart[node + 1] : 0;
  const int deg   = end - start;
  const int degA = __builtin_amdgcn_readfirstlane(deg);
  const int degB = __builtin_amdgcn_readlane(deg, 32);
  const int maxdeg = degA > degB ? degA : degB;

  const unsigned char* zp = z + f0;
  const unsigned short sv =
      hv ? *(const unsigned short*)(zp + (size_t)node * 64) : (unsigned short)0;

  float a00 = 0.f, a01 = 0.f, a10 = 0.f, a11 = 0.f;
  for (int w0 = 0; w0 < maxdeg; w0 += 32) {
    const int ei = start + w0 + il;
    const int safe = (ei < end) ? ei : (end > start ? end - 1 : 0);
    const int cidx = csr[safe];
    const int rem = maxdeg - w0;
    const int nloc = rem < 32 ? rem : 32;
    int j0 = 0;
    for (; j0 + 16 <= nloc; j0 += 16) {
      int idx[16];
      #pragma unroll
      for (int j = 0; j < 16; ++j)
        idx[j] = __shfl(cidx, (h << 5) + j0 + j, 64);
      unsigned short hh[16];
      #pragma unroll
      for (int j = 0; j < 16; ++j)
        hh[j] = *(const unsigned short*)(zp + (size_t)(unsigned)idx[j] * 64u);
      #pragma unroll
      for (int j = 0; j < 16; ++j) {
        const unsigned short m = (w0 + j0 + j < deg) ? hh[j] : (unsigned short)0;
        const floatx2 v = fp8x2tof(m);
        if (j & 1) { a10 += v.x; a11 += v.y; }
        else       { a00 += v.x; a01 += v.y; }
      }
    }
    for (; j0 + 4 <= nloc; j0 += 4) {
      int idx[4];
      #pragma unroll
      for (int j = 0; j < 4; ++j)
        idx[j] = __shfl(cidx, (h << 5) + j0 + j, 64);
      unsigned short hh[4];
      #pragma unroll
      for (int j = 0; j < 4; ++j)
        hh[j] = *(const unsigned short*)(zp + (size_t)(unsigned)idx[j] * 64u);
      #pragma unroll
      for (int j = 0; j < 4; ++j) {
        const unsigned short m = (w0 + j0 + j < deg) ? hh[j] : (unsigned short)0;
        const floatx2 v = fp8x2tof(m);
        if (j & 1) { a10 += v.x; a11 += v.y; }
        else       { a00 += v.x; a01 += v.y; }
      }
    }
    for (; j0 < nloc; ++j0) {
      const int idx = __shfl(cidx, (h << 5) + j0, 64);
      const unsigned short hh =
          *(const unsigned short*)(zp + (size_t)(unsigned)idx * 64u);
      const unsigned short m = (w0 + j0 < deg) ? hh : (unsigned short)0;
      const floatx2 v = fp8x2tof(m);
      a00 += v.x; a01 += v.y;
    }
  }
  if (hv) {
    const floatx2 sf = fp8x2tof(sv);
    const float2 bb = *(const float2*)(b + f0);
    float2 st;
    st.x = fmaxf(sf.x + bb.x + a00 + a10, 0.f);
    st.y = fmaxf(sf.y + bb.y + a01 + a11, 0.f);
    *(float2*)(agg + (size_t)node * 64 + f0) = st;
  }
}

// ------- gather_l2: o = relu(sum z2' - (deg+1)*cm2 + b2); z3 = o @ W3 (fp8) -------
// R19/R21 proven scalar form: one node/wave, 16/4/1 chunks, scalar-uniform
// csr, byte loads, HW fp8 decode; transposed-matvec epilogue. Every
// restructure lost (R15/R17/R20/R22) -- do not touch.
__global__ __launch_bounds__(256) void gather_l2_kernel(
    const unsigned char* __restrict__ z2, const float* __restrict__ b2,
    const float* __restrict__ W3, const float* __restrict__ cm2,
    const int* __restrict__ rowstart, const int* __restrict__ csr,
    unsigned char* __restrict__ z3, int N) {
  const int lane = threadIdx.x & 63;
  int node = blockIdx.x * (blockDim.x >> 6) + (threadIdx.x >> 6);
  if (node >= N) return;
  node = __builtin_amdgcn_readfirstlane(node);
  // stage W3 row `lane` early (independent of the gather; 4 VMEM total)
  float4 w4[4];
  #pragma unroll
  for (int q = 0; q < 4; ++q)
    w4[q] = ((const float4*)(W3 + lane * 16))[q];
  const float cml = cm2[lane];

  const int start = rowstart[node];
  const int end   = rowstart[node + 1];
  const unsigned char hs = z2[(size_t)node * 64 + lane];
  float a0 = 0.f, a1 = 0.f, a2 = 0.f, a3 = 0.f;
  int e = start;
  for (; e + 16 <= end; e += 16) {
    unsigned char h[16];
    #pragma unroll
    for (int j = 0; j < 16; ++j) h[j] = z2[(size_t)csr[e + j] * 64 + lane];
    #pragma unroll
    for (int j = 0; j < 16; j += 4) {
      a0 += fp8tof(h[j + 0]); a1 += fp8tof(h[j + 1]);
      a2 += fp8tof(h[j + 2]); a3 += fp8tof(h[j + 3]);
    }
  }
  for (; e + 4 <= end; e += 4) {
    unsigned char h[4];
    #pragma unroll
    for (int j = 0; j < 4; ++j) h[j] = z2[(size_t)csr[e + j] * 64 + lane];
    a0 += fp8tof(h[0]); a1 += fp8tof(h[1]); a2 += fp8tof(h[2]); a3 += fp8tof(h[3]);
  }
  for (; e < end; ++e) a0 += fp8tof(z2[(size_t)csr[e] * 64 + lane]);
  const float sum = (a0 + a1) + (a2 + a3);
  const float corr = (float)(end - start + 1) * cml;   // deg+1 rows pulled cm2
  const float o = fmaxf(fp8tof(hs) + b2[lane] + sum - corr, 0.f);

  // 16 partials: p[m] = o * W3[lane][m]
  float p[16];
  #pragma unroll
  for (int q = 0; q < 4; ++q) {
    p[4 * q + 0] = o * w4[q].x;
    p[4 * q + 1] = o * w4[q].y;
    p[4 * q + 2] = o * w4[q].z;
    p[4 * q + 3] = o * w4[q].w;
  }
  // split-butterfly: xor 1 (16->8), xor 2 (8->4), xor 4 (4->2), xor 8 (2->1)
  {
    const bool up = (lane & 1);
    #pragma unroll
    for (int m = 0; m < 8; ++m) {
      const float mine = up ? p[m + 8] : p[m];
      const float give = up ? p[m] : p[m + 8];
      p[m] = mine + __shfl_xor(give, 1, 64);
    }
  }
  {
    const bool up = (lane & 2);
    #pragma unroll
    for (int m = 0; m < 4; ++m) {
      const float mine = up ? p[m + 4] : p[m];
      const float give = up ? p[m] : p[m + 4];
      p[m] = mine + __shfl_xor(give, 2, 64);
    }
  }
  {
    const bool up = (lane & 4);
    #pragma unroll
    for (int m = 0; m < 2; ++m) {
      const float mine = up ? p[m + 2] : p[m];
      const float give = up ? p[m] : p[m + 2];
      p[m] = mine + __shfl_xor(give, 4, 64);
    }
  }
  {
    const bool up = (lane & 8);
    const float mine = up ? p[1] : p[0];
    const float give = up ? p[0] : p[1];
    p[0] = mine + __shfl_xor(give, 8, 64);
  }
  // pure reductions across remaining lane bits
  p[0] += __shfl_xor(p[0], 16, 64);
  p[0] += __shfl_xor(p[0], 32, 64);

  if (lane < 16) {
    // lane l holds output column bitrev4(l)
    const int j = ((lane & 1) << 3) | ((lane & 2) << 1) |
                  ((lane & 4) >> 1) | ((lane & 8) >> 3);
    z3[(size_t)node * 16 + j] = f2fp8(p[0]);
  }
}

// ------- gather16: out[d] = z3[d] + b3 + sum z3[src]; 16 feat x 4 edge-groups -------
__global__ __launch_bounds__(256) void gather16_kernel(
    const unsigned char* __restrict__ z3, const float* __restrict__ b3,
    const int* __restrict__ rowstart, const int* __restrict__ csr,
    float* __restrict__ out, int N) {
  const int lane = threadIdx.x & 63;
  const int f = lane & 15;
  const int g = lane >> 4;
  int node = blockIdx.x * (blockDim.x >> 6) + (threadIdx.x >> 6);
  if (node >= N) return;
  node = __builtin_amdgcn_readfirstlane(node);
  const int start = rowstart[node];
  const int end   = rowstart[node + 1];
  float acc0 = 0.f, acc1 = 0.f;
  int e = start + g;
  for (; e + 4 < end; e += 8) {
    acc0 += fp8tof(z3[(size_t)csr[e] * 16 + f]);
    acc1 += fp8tof(z3[(size_t)csr[e + 4] * 16 + f]);
  }
  if (e < end) acc0 += fp8tof(z3[(size_t)csr[e] * 16 + f]);
  float acc = acc0 + acc1;
  acc += __shfl_xor(acc, 16, 64);
  acc += __shfl_xor(acc, 32, 64);
  if (lane < 16)
    out[(size_t)node * 16 + f] = fp8tof(z3[(size_t)node * 16 + f]) + b3[f] + acc;
}

extern "C" void kernel_launch(void* const* d_in, const int* in_sizes, int n_in,
                              void* d_out, int out_size, void* d_ws, size_t ws_size,
                              hipStream_t stream) {
  const float* feat = (const float*)d_in[0];
  const float* W1 = (const float*)d_in[1];
  const float* b1 = (const float*)d_in[2];
  const float* W2 = (const float*)d_in[3];
  const float* b2 = (const float*)d_in[4];
  const float* W3 = (const float*)d_in[5];
  const float* b3 = (const float*)d_in[6];
  const int* src = (const int*)d_in[7];
  const int* dst = (const int*)d_in[8];
  const int N = in_sizes[0] / 64;
  const int E = in_sizes[7];
  float* out = (float*)d_out;

  // workspace layout
  float* B            = (float*)d_ws;                     // agg1, N*64 fp32
  unsigned char* zb   = (unsigned char*)(B + (size_t)N * 64);   // z1/z2' fp8 N*64
  unsigned char* z3b  = zb + (size_t)N * 64;              // z3, N*16 fp8
  int* cntA  = (int*)(z3b + (size_t)N * 16);              // NHB  } one memset
  float* cs1 = (float*)(cntA + NHB);                      // 64   } covers
  float* cs2 = cs1 + 64;                                  // 64   } these 3
  float* cm2w = cs2 + 64;                                 // 64 (no memset needed)
  int* baseA    = (int*)(cm2w + 64);                      // NHB+1
  int* curA     = baseA + NHB + 1;                        // NHB
  int* rowstart = curA + NHB;                             // N+1
  int* csr      = rowstart + N + 1;                       // E
  // ppack aliases zb+z3b (dead until matnorm1 writes zb, after fillsort):
  // E*4 = 6.4 MB <= N*64 (6.4 MB) + N*16 (1.6 MB)
  unsigned* ppack = (unsigned*)zb;

  const int NHI = (N + 1023) >> 10;     // 98
  const int node_blocks = (N + 3) / 4;  // 4 waves of 64 per block
  const int npairs = (N + 1) / 2;
  const int pair_blocks = (npairs + 3) / 4;  // 4 pair-waves per block
  const float invN = 1.0f / (float)N;

  // ---- CSR build + layer-1 colsum ----
  hipMemsetAsync(cntA, 0, (NHB + 128) * sizeof(int), stream);  // cntA+cs1+cs2
  prelude_kernel<<<512, 256, 0, stream>>>(dst, cntA, E, feat, cs1, N * 16);
  scanA_kernel<<<1, NHB, 0, stream>>>(cntA, baseA, curA, NHI);
  scatterA_kernel<<<512, 256, 0, stream>>>(src, dst, curA, ppack, E);
  fillsort_kernel<<<2 * NHI, 512, 0, stream>>>(ppack, baseA, rowstart, csr, N, E);

  // ---- layer 1 (split-lane pair gather) ----
  matnorm_kernel<<<1024, 256, 0, stream>>>(feat, W1, cs1, zb, N, invN);
  gather64_kernel<<<pair_blocks, 256, 0, stream>>>(zb, b1, rowstart, csr, B, N);

  // ---- layer 2: matnorm2 emits UNcentered z2' and accumulates cs2 itself ----
  matnorm2_kernel<<<1024, 256, 0, stream>>>(B, W2, cs2, zb, N);
  cm2_kernel<<<1, 64, 0, stream>>>(cs2, W2, cm2w, invN);
  gather_l2_kernel<<<node_blocks, 256, 0, stream>>>(zb, b2, W3, cm2w, rowstart,
                                                    csr, z3b, N);

  // ---- layer 3 final aggregation ----
  gather16_kernel<<<node_blocks, 256, 0, stream>>>(z3b, b3, rowstart, csr, out, N);
}